// Round 11
// baseline (176.322 us; speedup 1.0000x reference)
//
#include <hip/hip_runtime.h>
#include <hip/hip_fp16.h>

#define NFFT 3072
#define THREADS 256
#define HOP 192
#define HALF 1536
#define TFRAMES 1000
#define OUTLEN 191808
#define NBANDS 128
#define PI_F 3.14159265358979323846f
#define SEGLEN 3648               // 3072 + 3*HOP: four merged frames' OLA span
#define NSB 250                   // supersegments per batch (4 frames each)
#define SEGSTRIDE 768             // out-stride between supersegments

__device__ __forceinline__ float2 cadd(float2 a,float2 b){return make_float2(a.x+b.x,a.y+b.y);}
__device__ __forceinline__ float2 csub(float2 a,float2 b){return make_float2(a.x-b.x,a.y-b.y);}
__device__ __forceinline__ float2 cmul(float2 a,float2 b){
    return make_float2(fmaf(a.x,b.x,-a.y*b.y), fmaf(a.x,b.y,a.y*b.x));
}
__device__ __forceinline__ float2 cmuln_i(float2 a){return make_float2(a.y,-a.x);}  // a * (-i)
__device__ __forceinline__ float2 cneg(float2 a){return make_float2(-a.x,-a.y);}

// LDS padding: +1 float2 every 32 (256B). All FFT strides (192, 256) are
// multiples of 32, so padded strides stay exact: 192->198, 256->264.
__device__ __forceinline__ int IDXF(int i){ return i + (i>>5); }

__device__ __forceinline__ void dft4(float2 a0,float2 a1,float2 a2,float2 a3,
                                     float2&y0,float2&y1,float2&y2,float2&y3){
    float2 e0=cadd(a0,a2), e1=csub(a0,a2), o0=cadd(a1,a3), o1=csub(a1,a3);
    y0=cadd(e0,o0); y2=csub(e0,o0);
    float2 io=make_float2(-o1.y,o1.x);   // i*o1
    y1=csub(e1,io); y3=cadd(e1,io);
}
__device__ __forceinline__ void dft3(float2 a0,float2 a1,float2 a2,
                                     float2&y0,float2&y1,float2&y2){
    float2 s=cadd(a1,a2), d=csub(a1,a2);
    y0=cadd(a0,s);
    float2 t=make_float2(a0.x-0.5f*s.x, a0.y-0.5f*s.y);
    const float S3=0.86602540378443864676f;
    float2 id=make_float2(S3*d.y,-S3*d.x);   // -i*S3*d
    y1=cadd(t,id); y2=csub(t,id);
}

// 12-point DFT: o[j] = sum_l a[l] w12^{lj}.  12 = 4x3
__device__ __forceinline__ void dft12(float2 a[12], float2 o[12]){
    float2 u[3][4];
    #pragma unroll
    for(int n2=0;n2<3;++n2)
        dft4(a[n2],a[3+n2],a[6+n2],a[9+n2],u[n2][0],u[n2][1],u[n2][2],u[n2][3]);
    const float2 W1=make_float2( 0.86602540378443865f,-0.5f);
    const float2 W2=make_float2( 0.5f,-0.86602540378443865f);
    const float2 W4=make_float2(-0.5f,-0.86602540378443865f);
    u[1][1]=cmul(u[1][1],W1); u[1][2]=cmul(u[1][2],W2); u[1][3]=cmuln_i(u[1][3]);
    u[2][1]=cmul(u[2][1],W2); u[2][2]=cmul(u[2][2],W4); u[2][3]=cneg(u[2][3]);
    #pragma unroll
    for(int k1=0;k1<4;++k1)
        dft3(u[0][k1],u[1][k1],u[2][k1], o[k1],o[k1+4],o[k1+8]);
}

// 16-point DFT: 16 = 4x4
__device__ __forceinline__ void dft16(float2 a[16], float2 o[16]){
    float2 u[4][4];
    #pragma unroll
    for(int n2=0;n2<4;++n2)
        dft4(a[n2],a[4+n2],a[8+n2],a[12+n2],u[n2][0],u[n2][1],u[n2][2],u[n2][3]);
    const float C16=0.92387953251128674f, S16=0.38268343236508977f, R2=0.70710678118654752f;
    const float2 W1=make_float2( C16,-S16), W2=make_float2( R2,-R2), W3=make_float2( S16,-C16);
    const float2 W6=make_float2(-R2,-R2),  W9=make_float2(-C16, S16);
    u[1][1]=cmul(u[1][1],W1); u[1][2]=cmul(u[1][2],W2);   u[1][3]=cmul(u[1][3],W3);
    u[2][1]=cmul(u[2][1],W2); u[2][2]=cmuln_i(u[2][2]);   u[2][3]=cmul(u[2][3],W6);
    u[3][1]=cmul(u[3][1],W3); u[3][2]=cmul(u[3][2],W6);   u[3][3]=cmul(u[3][3],W9);
    #pragma unroll
    for(int k1=0;k1<4;++k1)
        dft4(u[0][k1],u[1][k1],u[2][k1],u[3][k1], o[k1],o[k1+4],o[k1+8],o[k1+12]);
}

// multiply o[j] *= w^j, w = e^{i*ang};  power tree
template<int R>
__device__ __forceinline__ void twiddle_pows(float2* o, float ang){
    float s,c; __sincosf(ang,&s,&c);
    float2 w1=make_float2(c,s);
    float2 w2=cmul(w1,w1);
    float2 w3=cmul(w2,w1);
    float2 w4=cmul(w2,w2);
    o[1]=cmul(o[1],w1); o[2]=cmul(o[2],w2); o[3]=cmul(o[3],w3);
    float2 w8=cmul(w4,w4);
    float2 w5=cmul(w4,w1), w6=cmul(w4,w2), w7=cmul(w4,w3);
    o[4]=cmul(o[4],w4); o[5]=cmul(o[5],w5); o[6]=cmul(o[6],w6); o[7]=cmul(o[7],w7);
    float2 w9=cmul(w8,w1), w10=cmul(w8,w2), w11=cmul(w8,w3);
    o[8]=cmul(o[8],w8); o[9]=cmul(o[9],w9); o[10]=cmul(o[10],w10); o[11]=cmul(o[11],w11);
    if constexpr (R>12){
        float2 w12=cmul(w8,w4), w13=cmul(w8,w5), w14=cmul(w8,w6), w15=cmul(w8,w7);
        o[12]=cmul(o[12],w12); o[13]=cmul(o[13],w13); o[14]=cmul(o[14],w14); o[15]=cmul(o[15],w15);
    }
}

// Stockham stage B: (NN=256, S=12, R=16); padded linear stride 192 -> 198
__device__ __forceinline__ void stageB(float2* __restrict__ A, int tid){
    const bool act = tid < 192;
    float2 o[16];
    int q=0,p=0;
    if(act){
        q = tid % 12; p = tid / 12;
        float2 a[16];
        int ib = IDXF(q + 12*p);
        #pragma unroll
        for(int l=0;l<16;++l) a[l] = A[ib + 198*l];
        dft16(a,o);
        twiddle_pows<16>(o, -2.0f*PI_F*(float)p*(1.0f/256.0f));
    }
    __syncthreads();
    if(act){
        #pragma unroll
        for(int j=0;j<16;++j) A[IDXF(q + 192*p + 12*j)] = o[j];
    }
    __syncthreads();
}

// One frame-pair: FFT -> filter -> IFFT -> window -> register-merged pair
// segment accumulated into LDS C at offset cb.  Fully straight-line when
// inlined with constant t0/cb (no runtime loop -> no scratch demotion).
__device__ __forceinline__ void process_pair(
    const float* __restrict__ nz, const float* __restrict__ fbb,
    float2* __restrict__ A, float* __restrict__ C, float* __restrict__ gf,
    const int tid, const int t0, const int cb, const bool act)
{
    __syncthreads();        // prev pair's phase-6 A reads / C-zero / gf reads done
    // gains: gf[0..127] frame t0, gf[128..255] frame t0+1
    gf[tid] = fbb[(size_t)(tid & 127)*TFRAMES + t0 + (tid >> 7)];

    const int base0 = t0*HOP - HALF;

    // ---- Phase 1: fwd stage A (NN=3072,S=1,R=12), global -> LDS ----
    {
        float2 a[12], o[12];
        #pragma unroll
        for(int l=0;l<12;++l){
            int i0 = base0 + tid + 256*l;
            float x0 = (i0 >= 0 && i0 < OUTLEN) ? nz[i0] : 0.0f;
            int i1 = i0 + HOP;
            float x1 = (i1 >= 0 && i1 < OUTLEN) ? nz[i1] : 0.0f;
            a[l] = make_float2(x0, x1);
        }
        dft12(a,o);
        twiddle_pows<12>(o, -2.0f*PI_F*(float)tid*(1.0f/3072.0f));
        #pragma unroll
        for(int j=0;j<12;++j) A[IDXF(12*tid + j)] = o[j];
    }
    __syncthreads();

    // ---- Phase 2: fwd stage B ----
    stageB(A, tid);

    // ---- Phase 3: fwd stage C (NN=16,S=192,R=16, no twiddle), in-place ----
    {
        float2 o[16];
        if(act){
            float2 a[16];
            int ib = IDXF(tid);
            #pragma unroll
            for(int l=0;l<16;++l) a[l] = A[ib + 198*l];
            dft16(a,o);
        }
        __syncthreads();
        if(act){
            int ib = IDXF(tid);
            #pragma unroll
            for(int j=0;j<16;++j) A[ib + 198*j] = o[j];
        }
        __syncthreads();
    }

    // ---- Phase 4: spectral multiply fused into inv stage A (R=12) ----
    // Z natural order: Z[k] at A[IDXF(k)]; linear stride 256 -> padded 264.
    // W'[k] = a_k*conj(Z[k]) + b_k*Z[N-k]
    {
        const int p = tid;
        float2 z[12], zm[12];
        {
            int ib = IDXF(p);
            #pragma unroll
            for(int l=0;l<12;++l) z[l] = A[ib + 264*l];     // Z[p + 256*l]
        }
        {
            int pm = (p==0) ? 0 : (256 - p);
            int ib = IDXF(pm);
            #pragma unroll
            for(int l=0;l<12;++l) zm[l] = A[ib + 264*l];    // Z[pm + 256*l]
        }
        float2 w[12];
        #pragma unroll
        for(int l=0;l<12;++l){
            int k = p + 256*l;
            int j = (k <= HALF) ? k : (NFFT - k);
            float aa = 0.0f, bb = 0.0f;
            if(j){
                int band = (j-1)/12;
                float Gx = gf[band], Gy = gf[NBANDS + band];
                aa = 0.5f*(Gx+Gy); bb = 0.5f*(Gx-Gy);
            }
            float2 Zm = (p==0) ? ((l==0) ? z[0] : z[12-l]) : zm[11-l];
            w[l] = make_float2( fmaf(aa, z[l].x,  bb*Zm.x),
                                fmaf(-aa, z[l].y, bb*Zm.y) );
        }
        float2 o[12];
        dft12(w,o);
        twiddle_pows<12>(o, -2.0f*PI_F*(float)p*(1.0f/3072.0f));
        __syncthreads();                        // all reads done before writes
        #pragma unroll
        for(int j=0;j<12;++j) A[IDXF(12*p + j)] = o[j];
        __syncthreads();
    }

    // ---- Phase 5: inv stage B ----
    stageB(A, tid);

    // ---- Phase 6: inv stage C + window + register pair-merge -> LDS C ----
    // pair-local c = tid+192j gets o[j].x (frame t0) and o[j-1].y (frame t0+1,
    // shifted HOP). Thread touches only C indices === tid (mod 192): no race.
    if(act){
        float2 a[16], o[16];
        int ib = IDXF(tid);
        #pragma unroll
        for(int l=0;l<16;++l) a[l] = A[ib + 198*l];
        dft16(a,o);
        const float invN = 1.0f/(float)NFFT;
        float prev_vy = 0.0f;
        #pragma unroll
        for(int j=0;j<17;++j){
            float val = prev_vy;
            if (j < 16){
                int n = tid + 192*j;
                float h = 0.5f - 0.5f*__cosf(2.0f*PI_F*(float)n*(1.0f/3071.0f));
                float s = invN*h;
                val    += o[j].x * s;
                prev_vy = -o[j].y * s;
            }
            C[cb + tid + 192*j] += val;
        }
    }
    // no trailing barrier; next pair's top barrier (or the flush barrier) covers it
}

// K1: 4 frames per block, two straight-line pair bodies accumulating into
// LDS C[3648]; flush once.  USE_WS: coalesced fp16 segment store (no atomics);
// else: coalesced atomics into out.
template<bool USE_WS>
__global__ __launch_bounds__(THREADS,4)
void filtered_noise_kernel(const float* __restrict__ fb,
                           const float* __restrict__ noise,
                           __half* __restrict__ ws,
                           float* __restrict__ out)
{
    __shared__ float2 A[NFFT + NFFT/32];   // 3168 float2 = 25344 B
    __shared__ float  C[SEGLEN];           // 14592 B
    __shared__ float  gf[2*NBANDS];        // 1024 B   -> total 40960 B = 4 blocks/CU

    const int tid = threadIdx.x;
    // XCD swizzle: grid 2000 = 8 x 250; blockIdx%8 -> XCD round robin pins each
    // batch's noise re-reads + output lines to one XCD's L2.
    const int b    = blockIdx.x & 7;
    const int sseg = blockIdx.x >> 3;      // supersegment 0..249
    const int T0   = 4*sseg;               // first frame of this block
    const float* nz  = noise + (size_t)b * OUTLEN;
    const float* fbb = fb + (size_t)b * NBANDS * TFRAMES;
    const int blockbase = T0*HOP - HALF;   // out index of combined sample 0
    const bool act = tid < 192;

    // zero the OLA accumulator (ordered before use by process_pair's top barrier)
    #pragma unroll
    for(int i=0;i<15;++i){
        int c = tid + 256*i;
        if (c < SEGLEN) C[c] = 0.0f;
    }

    process_pair(nz, fbb, A, C, gf, tid, T0,     0,   act);
    process_pair(nz, fbb, A, C, gf, tid, T0 + 2, 384, act);

    __syncthreads();                       // all C accumulation done

    if (USE_WS){
        __half* seg = ws + (size_t)(b*NSB + sseg)*SEGLEN;
        #pragma unroll
        for(int i=0;i<15;++i){
            int c = tid + 256*i;
            if (c < SEGLEN) seg[c] = __float2half(C[c]);
        }
    } else {
        float* outb = out + (size_t)b * OUTLEN;
        #pragma unroll
        for(int i=0;i<15;++i){
            int c = tid + 256*i;
            if (c < SEGLEN){
                int p = blockbase + c;
                if (p >= 0 && p < OUTLEN) atomicAdd(&outb[p], C[c]);
            }
        }
    }
}

// K2: overlap-add gather.  out[b][n] = sum of the <=5 fp16 supersegments
// covering n; accumulate f32, overwrite out (no memset needed).
// Supersegment s covers out [768*s - 1536, +3648); c = n + 1536 - 768*s.
__global__ __launch_bounds__(256)
void ola_reduce_kernel(const __half* __restrict__ ws, float* __restrict__ out)
{
    const int b = blockIdx.x & 7;          // XCD swizzle: batch per XCD
    const int n = (blockIdx.x >> 3)*256 + threadIdx.x;
    if (n >= OUTLEN) return;
    int tp1 = (n + HALF) / SEGSTRIDE;      if (tp1 > NSB-1) tp1 = NSB-1;
    int tp0 = (n > 2111) ? (n - 1344) / SEGSTRIDE : 0;   // ceil((n-2111)/768)
    const __half* wb = ws + (size_t)b*NSB*SEGLEN;
    float s = 0.0f;
    #pragma unroll
    for (int i = 0; i < 5; ++i){
        int tp = tp0 + i;
        if (tp <= tp1)
            s += __half2float(wb[tp*SEGLEN + (n + HALF - SEGSTRIDE*tp)]);
    }
    out[(size_t)b*OUTLEN + n] = s;
}

extern "C" void kernel_launch(void* const* d_in, const int* in_sizes, int n_in,
                              void* d_out, int out_size, void* d_ws, size_t ws_size,
                              hipStream_t stream)
{
    const float* fb    = (const float*)d_in[0];   // (8,1,128,1000) f32
    const float* noise = (const float*)d_in[1];   // (8,1,191808)   f32
    float* out = (float*)d_out;                   // (8,1,191808)   f32

    const int B = in_sizes[1] / OUTLEN;           // 8
    const size_t need = (size_t)B * NSB * SEGLEN * sizeof(__half);  // 14.6 MB

    dim3 grid1(B * NSB);                          // 2000 blocks, 4 frames each

    if (ws_size >= need){
        filtered_noise_kernel<true><<<grid1, THREADS, 0, stream>>>(
            fb, noise, (__half*)d_ws, out);
        dim3 grid2(B * ((OUTLEN + 255)/256));     // 8 x 750
        ola_reduce_kernel<<<grid2, 256, 0, stream>>>((const __half*)d_ws, out);
    } else {
        hipMemsetAsync(out, 0, (size_t)out_size * sizeof(float), stream);
        filtered_noise_kernel<false><<<grid1, THREADS, 0, stream>>>(
            fb, noise, nullptr, out);
    }
}